// Round 1
// baseline (830.801 us; speedup 1.0000x reference)
//
#include <hip/hip_runtime.h>
#include <hip/hip_bf16.h>
#include <math.h>

// Sizes from the reference
namespace {
constexpr int kNE   = 2048;
constexpr int kB    = 512;
constexpr int kDin  = 768;
constexpr int kD    = 512;
constexpr int kP    = 49;
constexpr int kNtot = kNE + kB;   // 2560
}

// ---------------------------------------------------------------------------
// Generic fp32 GEMM: C[M,N] = act(A[M,K] @ op(B) + bias)
//   BT=false: B stored [K,N] row-major.  BT=true: B stored [N,K] row-major.
// 64x64 tile, 256 threads, 4x4 micro-tile, K-tile = 16. Requires K % 16 == 0
// and K % 4 == 0 (true for all uses: K in {512, 768}).
// ---------------------------------------------------------------------------
template <bool BT, bool RELU>
__global__ __launch_bounds__(256) void gemm_f32(const float* __restrict__ A,
                                                const float* __restrict__ B,
                                                const float* __restrict__ bias,
                                                float* __restrict__ C,
                                                int M, int N, int K) {
  __shared__ float As[16][64];
  __shared__ float Bs[16][64];
  const int tid  = threadIdx.x;
  const int tx   = tid & 15;
  const int ty   = tid >> 4;
  const int row0 = blockIdx.y * 64;
  const int col0 = blockIdx.x * 64;

  float acc[4][4] = {};

  for (int k0 = 0; k0 < K; k0 += 16) {
    // ---- load A tile (transposed into LDS) ----
    {
      const int r  = tid >> 2;           // 0..63
      const int kk = (tid & 3) * 4;      // 0,4,8,12
      float4 v = make_float4(0.f, 0.f, 0.f, 0.f);
      const int grow = row0 + r;
      if (grow < M) v = *(const float4*)&A[(size_t)grow * K + k0 + kk];
      As[kk + 0][r] = v.x; As[kk + 1][r] = v.y;
      As[kk + 2][r] = v.z; As[kk + 3][r] = v.w;
    }
    // ---- load B tile ----
    if (!BT) {
      const int kk = tid >> 4;           // 0..15
      const int c  = (tid & 15) * 4;     // 0..60
      float4 v = make_float4(0.f, 0.f, 0.f, 0.f);
      const int gc = col0 + c;
      if (gc < N) v = *(const float4*)&B[(size_t)(k0 + kk) * N + gc];
      *(float4*)&Bs[kk][c] = v;
    } else {
      const int c  = tid >> 2;           // 0..63
      const int kk = (tid & 3) * 4;      // 0,4,8,12
      float4 v = make_float4(0.f, 0.f, 0.f, 0.f);
      const int gc = col0 + c;
      if (gc < N) v = *(const float4*)&B[(size_t)gc * K + k0 + kk];
      Bs[kk + 0][c] = v.x; Bs[kk + 1][c] = v.y;
      Bs[kk + 2][c] = v.z; Bs[kk + 3][c] = v.w;
    }
    __syncthreads();

#pragma unroll
    for (int kk = 0; kk < 16; ++kk) {
      float4 a = *(const float4*)&As[kk][ty * 4];
      float4 b = *(const float4*)&Bs[kk][tx * 4];
      float av[4] = {a.x, a.y, a.z, a.w};
      float bv[4] = {b.x, b.y, b.z, b.w};
#pragma unroll
      for (int i = 0; i < 4; ++i)
#pragma unroll
        for (int j = 0; j < 4; ++j) acc[i][j] = fmaf(av[i], bv[j], acc[i][j]);
    }
    __syncthreads();
  }

#pragma unroll
  for (int i = 0; i < 4; ++i) {
    const int grow = row0 + ty * 4 + i;
    if (grow >= M) continue;
#pragma unroll
    for (int j = 0; j < 4; ++j) {
      const int gc = col0 + tx * 4 + j;
      if (gc >= N) continue;
      float v = acc[i][j];
      if (bias) v += bias[gc];
      if (RELU) v = fmaxf(v, 0.f);
      C[(size_t)grow * N + gc] = v;
    }
  }
}

// ---------------------------------------------------------------------------
// Fused attention pooling over image tokens (the only use of the 385 MB).
// For row n: s[p] = scale * dot(toks[n,p,:], u[n,:]); a = softmax_p(s);
// ws768[n,:] = sum_p a[p] * toks[n,p,:].
// One block per n (2560 blocks, 256 threads = 4 waves).
// ---------------------------------------------------------------------------
__global__ __launch_bounds__(256) void attn_pool(
    const float* __restrict__ ent_toks, const float* __restrict__ men_toks,
    const float* __restrict__ u, float* __restrict__ ws768) {
  const int n = blockIdx.x;
  const float* toks = (n < kNE) ? ent_toks + (size_t)n * kP * kDin
                                : men_toks + (size_t)(n - kNE) * kP * kDin;
  const float* un = u + (size_t)n * kDin;

  __shared__ float sa[kP];
  const int wave = threadIdx.x >> 6;
  const int lane = threadIdx.x & 63;

  // phase 1: scores
  for (int p = wave; p < kP; p += 4) {
    const float* tp = toks + (size_t)p * kDin;
    float acc = 0.f;
#pragma unroll
    for (int r = 0; r < 3; ++r) {
      float4 t  = *(const float4*)&tp[lane * 4 + r * 256];
      float4 uu = *(const float4*)&un[lane * 4 + r * 256];
      acc = fmaf(t.x, uu.x, acc); acc = fmaf(t.y, uu.y, acc);
      acc = fmaf(t.z, uu.z, acc); acc = fmaf(t.w, uu.w, acc);
    }
    for (int o = 32; o; o >>= 1) acc += __shfl_xor(acc, o);
    if (lane == 0) sa[p] = acc * 0.044194173824159216f;  // 512^-0.5
  }
  __syncthreads();

  // phase 2: softmax over 49 (wave 0)
  if (wave == 0) {
    float v = (lane < kP) ? sa[lane] : -INFINITY;
    float m = v;
    for (int o = 32; o; o >>= 1) m = fmaxf(m, __shfl_xor(m, o));
    float e = (lane < kP) ? expf(v - m) : 0.f;
    float s = e;
    for (int o = 32; o; o >>= 1) s += __shfl_xor(s, o);
    if (lane < kP) sa[lane] = e / s;
  }
  __syncthreads();

  // phase 3: weighted sum (re-reads block's 150 KB, mostly L2-resident)
  const int j = threadIdx.x;
  float a0 = 0.f, a1 = 0.f, a2 = 0.f;
  for (int p = 0; p < kP; ++p) {
    const float ap = sa[p];
    const float* tp = toks + (size_t)p * kDin;
    a0 = fmaf(ap, tp[j], a0);
    a1 = fmaf(ap, tp[j + 256], a1);
    a2 = fmaf(ap, tp[j + 512], a2);
  }
  float* wr = ws768 + (size_t)n * kDin;
  wr[j] = a0; wr[j + 256] = a1; wr[j + 512] = a2;
}

// ---------------------------------------------------------------------------
// MoE gate: gate[n,:] = softmax( concat(txt[n], img[n]) @ gw + gb )
// One block (1 wave) per n.
// ---------------------------------------------------------------------------
__global__ __launch_bounds__(64) void moe_gate(
    const float* __restrict__ txt, const float* __restrict__ img,
    const float* __restrict__ gw, const float* __restrict__ gb,
    float* __restrict__ gate2) {
  const int n = blockIdx.x;
  const int lane = threadIdx.x;
  float a0 = 0.f, a1 = 0.f;
  for (int k = lane; k < kD; k += 64) {
    const float t = txt[(size_t)n * kD + k];
    a0 = fmaf(t, gw[k * 2 + 0], a0);
    a1 = fmaf(t, gw[k * 2 + 1], a1);
    const float im = img[(size_t)n * kD + k];
    a0 = fmaf(im, gw[(kD + k) * 2 + 0], a0);
    a1 = fmaf(im, gw[(kD + k) * 2 + 1], a1);
  }
  for (int o = 32; o; o >>= 1) { a0 += __shfl_xor(a0, o); a1 += __shfl_xor(a1, o); }
  if (lane == 0) {
    const float l0 = a0 + gb[0], l1 = a1 + gb[1];
    const float m = fmaxf(l0, l1);
    const float e0 = expf(l0 - m), e1 = expf(l1 - m);
    const float inv = 1.f / (e0 + e1);
    gate2[n * 2 + 0] = e0 * inv;
    gate2[n * 2 + 1] = e1 * inv;
  }
}

// ---------------------------------------------------------------------------
// Finalize: gt = tanh(cls_p[n]·gfw + gfb); y = cls_p*gt + g0*et + g1*ei;
// out = LN(y)*ln_g + ln_b.  One block (256 thr) per n, 2 elems per thread.
// ---------------------------------------------------------------------------
__global__ __launch_bounds__(256) void finalize_ln(
    const float* __restrict__ cls_p, const float* __restrict__ et,
    const float* __restrict__ ei, const float* __restrict__ gate2,
    const float* __restrict__ gfw, const float* __restrict__ gfb,
    const float* __restrict__ lng, const float* __restrict__ lnb,
    float* __restrict__ outp) {
  const int n = blockIdx.x;
  const int t = threadIdx.x;
  const int lane = t & 63, wave = t >> 6;
  const float* cp = cls_p + (size_t)n * kD;
  const float c0 = cp[t], c1 = cp[t + 256];

  // tanh gate: block-reduce dot(cls_p[n], gfw)
  float d = fmaf(c0, gfw[t], c1 * gfw[t + 256]);
  for (int o = 32; o; o >>= 1) d += __shfl_xor(d, o);
  __shared__ float rs[4];
  __shared__ float gtb;
  if (lane == 0) rs[wave] = d;
  __syncthreads();
  if (t == 0) gtb = tanhf(rs[0] + rs[1] + rs[2] + rs[3] + gfb[0]);
  __syncthreads();
  const float gt = gtb;
  const float g0 = gate2[n * 2 + 0], g1 = gate2[n * 2 + 1];

  const size_t base = (size_t)n * kD;
  const float y0 = c0 * gt + g0 * et[base + t]       + g1 * ei[base + t];
  const float y1 = c1 * gt + g0 * et[base + 256 + t] + g1 * ei[base + 256 + t];

  float s = y0 + y1, ss = fmaf(y0, y0, y1 * y1);
  for (int o = 32; o; o >>= 1) { s += __shfl_xor(s, o); ss += __shfl_xor(ss, o); }
  __shared__ float rsum[4], rssq[4];
  __shared__ float mb, ivb;
  if (lane == 0) { rsum[wave] = s; rssq[wave] = ss; }
  __syncthreads();
  if (t == 0) {
    const float S  = rsum[0] + rsum[1] + rsum[2] + rsum[3];
    const float SS = rssq[0] + rssq[1] + rssq[2] + rssq[3];
    const float m  = S / (float)kD;
    const float v  = SS / (float)kD - m * m;
    mb = m; ivb = rsqrtf(v + 1e-5f);
  }
  __syncthreads();
  const float m = mb, iv = ivb;
  outp[base + t]       = (y0 - m) * iv * lng[t] + lnb[t];
  outp[base + 256 + t] = (y1 - m) * iv * lng[t + 256] + lnb[t + 256];
}

// ---------------------------------------------------------------------------
extern "C" void kernel_launch(void* const* d_in, const int* in_sizes, int n_in,
                              void* d_out, int out_size, void* d_ws, size_t ws_size,
                              hipStream_t stream) {
  const float* ent_cls  = (const float*)d_in[0];
  const float* ent_tok  = (const float*)d_in[1];
  const float* men_cls  = (const float*)d_in[2];
  const float* men_tok  = (const float*)d_in[3];
  const float* text_w   = (const float*)d_in[4];
  const float* text_b   = (const float*)d_in[5];
  const float* img_w    = (const float*)d_in[6];
  const float* img_b    = (const float*)d_in[7];
  const float* gate_w   = (const float*)d_in[8];
  const float* gate_b   = (const float*)d_in[9];
  const float* ln_g     = (const float*)d_in[10];
  const float* ln_b     = (const float*)d_in[11];
  const float* match_w  = (const float*)d_in[12];
  const float* match_b  = (const float*)d_in[13];
  // d_in[14..18] (mh_query, mh_wq, mh_bq, mh_wk, mh_bk) provably unused
  const float* mh_wv    = (const float*)d_in[19];
  const float* mh_bv    = (const float*)d_in[20];
  const float* mh_wo    = (const float*)d_in[21];
  const float* mh_bo    = (const float*)d_in[22];
  const float* moe_gw   = (const float*)d_in[23];
  const float* moe_gb   = (const float*)d_in[24];
  const float* moe_tw1  = (const float*)d_in[25];
  const float* moe_tb1  = (const float*)d_in[26];
  const float* moe_tw2  = (const float*)d_in[27];
  const float* moe_tb2  = (const float*)d_in[28];
  const float* moe_iw1  = (const float*)d_in[29];
  const float* moe_ib1  = (const float*)d_in[30];
  const float* moe_iw2  = (const float*)d_in[31];
  const float* moe_ib2  = (const float*)d_in[32];

  float* w = (float*)d_ws;
  size_t o = 0;
  auto alloc = [&](size_t nf) { size_t r = o; o += (nf + 127) & ~(size_t)127; return r; };
  const size_t o_clsp  = alloc((size_t)kNtot * kD);    // [2560,512]
  const size_t o_u_ht  = alloc((size_t)kNtot * kDin);  // u, reused as h_t
  const size_t o_ws_hi = alloc((size_t)kNtot * kDin);  // ws768, reused as h_i
  const size_t o_txt   = alloc((size_t)kNtot * kD);
  const size_t o_img   = alloc((size_t)kNtot * kD);
  const size_t o_et    = alloc((size_t)kNtot * kD);
  const size_t o_ei    = alloc((size_t)kNtot * kD);
  const size_t o_ctx   = alloc((size_t)kNtot * kD);    // e_ctx rows 0..2047, m_ctx 2048..2559
  const size_t o_Wcomb = alloc((size_t)kDin * kD);
  const size_t o_bcomb = alloc(kD);
  const size_t o_T1    = alloc((size_t)kD * kD);
  const size_t o_Wimg  = alloc((size_t)kD * kD);
  const size_t o_bt1   = alloc(kD);
  const size_t o_bimg  = alloc(kD);
  const size_t o_gate  = alloc((size_t)kNtot * 2);
  (void)ws_size; (void)n_in; (void)in_sizes; (void)out_size;

  auto cdiv = [](int a, int b) { return (a + b - 1) / b; };
  auto G = [&](int M, int N) { return dim3((unsigned)cdiv(N, 64), (unsigned)cdiv(M, 64)); };

  // 1. cls_p = cls @ text_fc_w + text_fc_b  (both sides into one buffer)
  hipLaunchKernelGGL((gemm_f32<false, false>), G(kNE, kD), 256, 0, stream,
                     ent_cls, text_w, text_b, w + o_clsp, kNE, kD, kDin);
  hipLaunchKernelGGL((gemm_f32<false, false>), G(kB, kD), 256, 0, stream,
                     men_cls, text_w, text_b, w + o_clsp + (size_t)kNE * kD, kB, kD, kDin);

  // 2. u = cls_p @ image_fc_w^T   (B stored [768,512], BT)
  hipLaunchKernelGGL((gemm_f32<true, false>), G(kNtot, kDin), 256, 0, stream,
                     w + o_clsp, img_w, (const float*)nullptr, w + o_u_ht, kNtot, kDin, kD);

  // 3. softmax-weighted token pooling -> ws768
  hipLaunchKernelGGL(attn_pool, dim3(kNtot), 256, 0, stream,
                     ent_tok, men_tok, w + o_u_ht, w + o_ws_hi);

  // 4. Wcomb = image_fc_w @ match_w ; bcomb = image_fc_b @ match_w + match_b
  hipLaunchKernelGGL((gemm_f32<false, false>), G(kDin, kD), 256, 0, stream,
                     img_w, match_w, (const float*)nullptr, w + o_Wcomb, kDin, kD, kD);
  hipLaunchKernelGGL((gemm_f32<false, false>), G(1, kD), 256, 0, stream,
                     img_b, match_w, match_b, w + o_bcomb, 1, kD, kD);

  // 5. txt = ws768 @ Wcomb + bcomb
  hipLaunchKernelGGL((gemm_f32<false, false>), G(kNtot, kD), 256, 0, stream,
                     w + o_ws_hi, w + o_Wcomb, w + o_bcomb, w + o_txt, kNtot, kD, kDin);

  // 6. image branch collapses: W_img = match_w@wv@wo, b_img = (match_b@wv+bv)@wo+bo
  hipLaunchKernelGGL((gemm_f32<false, false>), G(kD, kD), 256, 0, stream,
                     match_w, mh_wv, (const float*)nullptr, w + o_T1, kD, kD, kD);
  hipLaunchKernelGGL((gemm_f32<false, false>), G(kD, kD), 256, 0, stream,
                     w + o_T1, mh_wo, (const float*)nullptr, w + o_Wimg, kD, kD, kD);
  hipLaunchKernelGGL((gemm_f32<false, false>), G(1, kD), 256, 0, stream,
                     match_b, mh_wv, mh_bv, w + o_bt1, 1, kD, kD);
  hipLaunchKernelGGL((gemm_f32<false, false>), G(1, kD), 256, 0, stream,
                     w + o_bt1, mh_wo, mh_bo, w + o_bimg, 1, kD, kD);
  hipLaunchKernelGGL((gemm_f32<false, false>), G(kNtot, kD), 256, 0, stream,
                     w + o_clsp, w + o_Wimg, w + o_bimg, w + o_img, kNtot, kD, kD);

  // 7. MoE gate
  hipLaunchKernelGGL(moe_gate, dim3(kNtot), 64, 0, stream,
                     w + o_txt, w + o_img, moe_gw, moe_gb, w + o_gate);

  // 8. experts
  hipLaunchKernelGGL((gemm_f32<false, true>), G(kNtot, kD), 256, 0, stream,
                     w + o_txt, moe_tw1, moe_tb1, w + o_u_ht, kNtot, kD, kD);
  hipLaunchKernelGGL((gemm_f32<false, false>), G(kNtot, kD), 256, 0, stream,
                     w + o_u_ht, moe_tw2, moe_tb2, w + o_et, kNtot, kD, kD);
  hipLaunchKernelGGL((gemm_f32<false, true>), G(kNtot, kD), 256, 0, stream,
                     w + o_img, moe_iw1, moe_ib1, w + o_ws_hi, kNtot, kD, kD);
  hipLaunchKernelGGL((gemm_f32<false, false>), G(kNtot, kD), 256, 0, stream,
                     w + o_ws_hi, moe_iw2, moe_ib2, w + o_ei, kNtot, kD, kD);

  // 9. gate-tanh + combine + LayerNorm -> ctx (e_ctx | m_ctx)
  hipLaunchKernelGGL(finalize_ln, dim3(kNtot), 256, 0, stream,
                     w + o_clsp, w + o_et, w + o_ei, w + o_gate,
                     gate_w, gate_b, ln_g, ln_b, w + o_ctx);

  // 10. out = m_ctx @ e_ctx^T   [512, 2048]
  hipLaunchKernelGGL((gemm_f32<true, false>), G(kB, kNE), 256, 0, stream,
                     w + o_ctx + (size_t)kNE * kD, w + o_ctx, (const float*)nullptr,
                     (float*)d_out, kB, kNE, kD);
}